// Round 14
// baseline (338.570 us; speedup 1.0000x reference)
//
#include <hip/hip_runtime.h>
#include <hip/hip_bf16.h>
#include <math.h>

#define BATCH 2
#define CCH   512
#define NSP   4096
#define NHEAD 8
#define HDIM  64
#define NGRP  32
#define CPG   16
#define EPSV  1e-5f
#define NSPLIT 2
#define MTN   (NSP / NSPLIT / 64)
#define SMSCALE 0.1803368801111204f   // 0.125 * log2(e): folded into Q at QKV epilogue

typedef __attribute__((ext_vector_type(8))) short short8;
typedef __attribute__((ext_vector_type(4))) short short4v;
typedef __attribute__((ext_vector_type(4))) float f32x4;
typedef __hip_bfloat16 bf16;

// pack two fp32 -> two bf16 in a u32 (approx-RNE via +0x8000; no NaN/Inf in our paths)
static __device__ __forceinline__ unsigned pk2(float a, float b) {
    return ((__float_as_uint(a) + 0x8000u) >> 16) |
           ((__float_as_uint(b) + 0x8000u) & 0xFFFF0000u);
}
static __device__ __forceinline__ unsigned pk1(float a) {
    return (__float_as_uint(a) + 0x8000u) >> 16;
}
static __device__ __forceinline__ float upk(unsigned u) {   // low 16 bits -> float
    unsigned v = u << 16;
    return __uint_as_float(v);
}
static __device__ __forceinline__ float fexp2(float x) {
    return __builtin_amdgcn_exp2f(x);   // v_exp_f32, 1 instr
}
// async global->LDS, 16B per lane. LDS base must be WAVE-UNIFORM; HW writes
// lane i's 16B at base + i*16. Global src is per-lane.
static __device__ __forceinline__ void gload16(const bf16* g, bf16* l) {
    __builtin_amdgcn_global_load_lds(
        (const __attribute__((address_space(1))) unsigned*)g,
        (__attribute__((address_space(3))) unsigned*)l, 16, 0, 0);
}

// ---------------- fused: GroupNorm partial stats (blocks 0..1023) + weight cast ----------------
__global__ __launch_bounds__(256) void prep0(const float* __restrict__ x,
                                             const float* __restrict__ qkvw,
                                             const float* __restrict__ pw,
                                             float* __restrict__ sbuf,
                                             bf16* __restrict__ wq, bf16* __restrict__ wp) {
    if (blockIdx.x < 1024) {
        const int bg = blockIdx.x >> 4, sub = blockIdx.x & 15;
        const float4* p = (const float4*)(x + (size_t)bg * (CPG * NSP)) +
                          (size_t)sub * (CPG * NSP / 4 / 16);
        float s = 0.f, ss = 0.f;
#pragma unroll
        for (int it = 0; it < 4; it++) {                 // 1024 float4 / 256 threads
            float4 v = p[it * 256 + threadIdx.x];
            s  += v.x + v.y + v.z + v.w;
            ss += v.x * v.x + v.y * v.y + v.z * v.z + v.w * v.w;
        }
        for (int o = 32; o > 0; o >>= 1) {
            s  += __shfl_down(s, o);
            ss += __shfl_down(ss, o);
        }
        __shared__ float shs[4], shss[4];
        const int wid = threadIdx.x >> 6, lane = threadIdx.x & 63;
        if (lane == 0) { shs[wid] = s; shss[wid] = ss; }
        __syncthreads();
        if (threadIdx.x == 0) {
            s  = shs[0] + shs[1] + shs[2] + shs[3];
            ss = shss[0] + shss[1] + shss[2] + shss[3];
            sbuf[bg * 16 + sub]        = s;
            sbuf[1024 + bg * 16 + sub] = ss;
        }
    } else {
        const int i = (blockIdx.x - 1024) * 256 + threadIdx.x;   // float4 index
        const int NQ = 1536 * 512 / 4;
        float4 v; bf16* dst; int di;
        if (i < NQ) { v = ((const float4*)qkvw)[i]; dst = wq; di = i; }
        else        { v = ((const float4*)pw)[i - NQ]; dst = wp; di = i - NQ; }
        uint2 o = {pk2(v.x, v.y), pk2(v.z, v.w)};
        *(uint2*)(dst + (size_t)di * 4) = o;
    }
}

// ---------------- GroupNorm finalize + apply + transpose + cast: hnt[b][n][c] bf16 ----------------
__global__ __launch_bounds__(256) void gn_apply_t(const float* __restrict__ x,
                                                  const float* __restrict__ sbuf,
                                                  const float* __restrict__ nw,
                                                  const float* __restrict__ nb,
                                                  bf16* __restrict__ hnt) {
    __shared__ float Ls[64][68];
    __shared__ float Gmu[4], Grs[4];
    const int b  = blockIdx.z;
    const int c0 = blockIdx.y * 64;
    const int n0 = blockIdx.x * 64;
    const int t  = threadIdx.x;
    const int cl = t >> 4, n4 = (t & 15) * 4;
    if (t < 4) {
        const int bg = b * NGRP + (c0 >> 4) + t;
        float s = 0.f, ss = 0.f;
#pragma unroll
        for (int i = 0; i < 16; i++) {
            s  += sbuf[bg * 16 + i];
            ss += sbuf[1024 + bg * 16 + i];
        }
        const float invn = 1.f / (float)(CPG * NSP);
        const float mu = s * invn;
        Gmu[t] = mu;
        Grs[t] = rsqrtf(ss * invn - mu * mu + EPSV);
    }
    __syncthreads();
#pragma unroll
    for (int ph = 0; ph < 4; ph++) {
        const int c  = c0 + ph * 16 + cl;
        const float mu = Gmu[ph], rs = Grs[ph];
        const float sw = nw[c] * rs;
        const float sb = nb[c] - mu * sw;
        float4 v = *(const float4*)&x[((size_t)b * CCH + c) * NSP + n0 + n4];
        float4 o;
        o.x = v.x * sw + sb; o.y = v.y * sw + sb;
        o.z = v.z * sw + sb; o.w = v.w * sw + sb;
        *(float4*)&Ls[ph * 16 + cl][n4] = o;
    }
    __syncthreads();
#pragma unroll
    for (int ph = 0; ph < 2; ph++) {
        const int task = ph * 256 + t;
        const int nl = task & 63, cc = (task >> 6) * 8;
        uint4 o;
        o.x = pk2(Ls[cc + 0][nl], Ls[cc + 1][nl]);
        o.y = pk2(Ls[cc + 2][nl], Ls[cc + 3][nl]);
        o.z = pk2(Ls[cc + 4][nl], Ls[cc + 5][nl]);
        o.w = pk2(Ls[cc + 6][nl], Ls[cc + 7][nl]);
        *(uint4*)&hnt[((size_t)b * NSP + n0 + nl) * CCH + c0 + cc] = o;
    }
}

// ---------------- bf16 MFMA GEMM v2 (128x128): LDS double-buffer + global_load_lds ----------------
#define GEMM_STAGE(CUR)                                         \
    gload16(aSrc0, &As[CUR][(wave * 16) * 32]);                 \
    gload16(aSrc1, &As[CUR][(64 + wave * 16) * 32]);            \
    gload16(bSrc0, &Bs[CUR][(wave * 16) * 32]);                 \
    gload16(bSrc1, &Bs[CUR][(64 + wave * 16) * 32]);            \
    aSrc0 += 32; aSrc1 += 32; bSrc0 += 32; bSrc1 += 32;

#define GEMM_MAIN(Wptr, Xptr)                                                            \
    __shared__ __align__(16) bf16 As[2][128 * 32];                                       \
    __shared__ __align__(16) bf16 Bs[2][128 * 32];                                       \
    const int t = threadIdx.x, wave = t >> 6, lane = t & 63;                             \
    const int quad = lane >> 4, l15 = lane & 15;                                         \
    const int srow = lane >> 2, scol = (lane & 3) * 8;                                   \
    const int b   = blockIdx.z;                                                          \
    const int wm = wave >> 1, wn = wave & 1;                                             \
    const int m0w = blockIdx.y * 128 + wm * 64;                                          \
    const int n0w = blockIdx.x * 128 + wn * 64;                                          \
    const bf16* aSrc0 = Wptr + (size_t)(blockIdx.y * 128 + wave * 16 + srow) * 512 + scol; \
    const bf16* aSrc1 = aSrc0 + (size_t)64 * 512;                                        \
    const bf16* bSrc0 = Xptr + ((size_t)b * NSP + blockIdx.x * 128 + wave * 16 + srow) * 512 + scol; \
    const bf16* bSrc1 = bSrc0 + (size_t)64 * 512;                                        \
    f32x4 acc[4][4];                                                                     \
    _Pragma("unroll")                                                                    \
    for (int i = 0; i < 4; i++)                                                          \
        _Pragma("unroll")                                                                \
        for (int j = 0; j < 4; j++) acc[i][j] = (f32x4){0.f, 0.f, 0.f, 0.f};             \
    GEMM_STAGE(0)                                                                        \
    __syncthreads();                                                                     \
    _Pragma("unroll")                                                                    \
    for (int ks = 0; ks < 16; ks++) {                                                    \
        const int cur = ks & 1;                                                          \
        if (ks < 15) { GEMM_STAGE(cur ^ 1) }                                             \
        short8 af[4], bfr[4];                                                            \
        _Pragma("unroll")                                                                \
        for (int mf = 0; mf < 4; mf++)                                                   \
            af[mf] = *(const short8*)&As[cur][(wm * 64 + mf * 16 + l15) * 32 + quad * 8]; \
        _Pragma("unroll")                                                                \
        for (int nf = 0; nf < 4; nf++)                                                   \
            bfr[nf] = *(const short8*)&Bs[cur][(wn * 64 + nf * 16 + l15) * 32 + quad * 8]; \
        _Pragma("unroll")                                                                \
        for (int mf = 0; mf < 4; mf++)                                                   \
            _Pragma("unroll")                                                            \
            for (int nf = 0; nf < 4; nf++)                                               \
                acc[mf][nf] = __builtin_amdgcn_mfma_f32_16x16x32_bf16(af[mf], bfr[nf],   \
                                                                      acc[mf][nf], 0, 0, 0); \
        __syncthreads();                                                                 \
    }

__global__ __launch_bounds__(256) void gemm_qkv(const bf16* __restrict__ Wb,
                                                const bf16* __restrict__ Xt,
                                                const float* __restrict__ bias,
                                                bf16* __restrict__ qt, bf16* __restrict__ kt,
                                                bf16* __restrict__ vt) {
    GEMM_MAIN(Wb, Xt)

    const int sec = m0w >> 9, h = (m0w >> 6) & 7, bh = b * NHEAD + h;
    const float sm = (sec == 0) ? SMSCALE : 1.0f;
    float bi[4][4];
#pragma unroll
    for (int mf = 0; mf < 4; mf++)
#pragma unroll
        for (int r = 0; r < 4; r++) bi[mf][r] = bias[m0w + mf * 16 + quad * 4 + r];

    if (sec < 2) {
        bf16* dst = (sec == 0) ? qt : kt;   // [bh][n][d], d = mf*16+quad*4+r: 4 consecutive
#pragma unroll
        for (int mf = 0; mf < 4; mf++)
#pragma unroll
            for (int nf = 0; nf < 4; nf++) {
                const int n = n0w + nf * 16 + l15;
                float v0 = (acc[mf][nf][0] + bi[mf][0]) * sm;
                float v1 = (acc[mf][nf][1] + bi[mf][1]) * sm;
                float v2 = (acc[mf][nf][2] + bi[mf][2]) * sm;
                float v3 = (acc[mf][nf][3] + bi[mf][3]) * sm;
                uint2 o = {pk2(v0, v1), pk2(v2, v3)};
                *(uint2*)(dst + ((size_t)bh * NSP + n) * HDIM + mf * 16 + quad * 4) = o;
            }
    } else {
#pragma unroll
        for (int mf = 0; mf < 4; mf++)
#pragma unroll
            for (int nf = 0; nf < 4; nf++)
#pragma unroll
                for (int r = 0; r < 4; r++) {
                    const float v = acc[mf][nf][r] + bi[mf][r];
                    const int n = n0w + nf * 16 + l15;
                    const int d = mf * 16 + quad * 4 + r;
                    unsigned u = pk1(v);
                    vt[((size_t)bh * HDIM + d) * NSP + n] = *(bf16*)&u;
                }
    }
}

// r13: LDS-transposed epilogue for proj — perfect float4 streams on out/resid.
__global__ __launch_bounds__(256) void gemm_proj(const bf16* __restrict__ Wb,
                                                 const bf16* __restrict__ Xt,
                                                 const float* __restrict__ bias,
                                                 const float* __restrict__ resid,
                                                 float* __restrict__ out) {
    GEMM_MAIN(Wb, Xt)

    float bi[4][4];
#pragma unroll
    for (int mf = 0; mf < 4; mf++)
#pragma unroll
        for (int r = 0; r < 4; r++) bi[mf][r] = bias[m0w + mf * 16 + quad * 4 + r];

    float* scratch = (float*)As;         // 4096 fp32; safe after final barrier
    const int n0 = blockIdx.x * 128;
#pragma unroll
    for (int p = 0; p < 4; p++) {
        if (wm == (p >> 1)) {
#pragma unroll
            for (int ml = 0; ml < 2; ml++) {
                const int mf = (p & 1) * 2 + ml;
#pragma unroll
                for (int nf = 0; nf < 4; nf++)
#pragma unroll
                    for (int r = 0; r < 4; r++)
                        scratch[(ml * 16 + quad * 4 + r) * 128 + wn * 64 + nf * 16 + l15] =
                            acc[mf][nf][r] + bi[mf][r];
            }
        }
        __syncthreads();
#pragma unroll
        for (int i = 0; i < 4; i++) {
            const int idx = i * 256 + t;     // 0..1023
            const int row = idx >> 5, c4 = idx & 31;
            const int m = blockIdx.y * 128 + p * 32 + row;
            const size_t off = ((size_t)b * CCH + m) * NSP + n0 + c4 * 4;
            float4 rv = *(const float4*)&resid[off];
            float4 sv = *(const float4*)&scratch[row * 128 + c4 * 4];
            float4 ov;
            ov.x = sv.x + rv.x; ov.y = sv.y + rv.y;
            ov.z = sv.z + rv.z; ov.w = sv.w + rv.w;
            *(float4*)&out[off] = ov;
        }
        __syncthreads();
    }
}

// ---------------- MFMA flash attention v15: VALU rowsum replaces ol-MFMAs ----------------
// r13 analysis: the ones-vector rowsum spent 2 of 18 MFMAs/qs (11% of issue) at
// the TAIL of each qs chain. VALUBusy is 43% (slack) and lsum is only consumed
// in the epilogue — so compute ps = sum(e) during exp2 (registers already live),
// butterfly across the 4 quads sharing a query column (__shfl_xor 16/32, DS pipe,
// off critical path), accumulate lsum[qs]. onesf/ol deleted; lpart layout kept.
__global__ __launch_bounds__(256, 2) void attn10(const bf16* __restrict__ qt,
                                                 const bf16* __restrict__ kt,
                                                 const bf16* __restrict__ vt,
                                                 bf16* __restrict__ opart,
                                                 float* __restrict__ lpart) {
    __shared__ __align__(16) bf16 Ks[2][64][68];
    __shared__ __align__(16) bf16 Vs[2][64][68];
    const int t = threadIdx.x, wave = t >> 6, lane = t & 63;
    const int quad = lane >> 4, l15 = lane & 15;
    const int blk = blockIdx.x;            // 0..511
    const int xcd = blk & 7, slot = blk >> 3;       // slot 0..63
    const int qtile = slot & 15;                    // 16 q-tiles of 256
    const int grp = xcd + 8 * (slot >> 4);          // 0..31 = (bh, spl)
    const int spl = grp & 1, bh = grp >> 1;
    const int b = bh >> 3, h = bh & 7;
    const int qb  = qtile * 256 + wave * 64;
    const int kb0 = spl * (NSP / NSPLIT);

    const bf16* Qb = qt + (size_t)bh * NSP * HDIM;

    // staging assignment: thread t -> 4 x 16B chunks (2 K row-halves, 2 V)
    const int trow = t >> 3;          // 0..31
    const int tcol = (t & 7) * 8;     // element offset in 64-elem row
    const bf16* kSrcA = kt + (size_t)bh * NSP * HDIM + (size_t)(kb0 + trow) * HDIM + tcol;
    const bf16* kSrcB = kSrcA + 32 * HDIM;
    const bf16* vSrcA = vt + (size_t)bh * HDIM * NSP + (size_t)trow * NSP + kb0 + tcol;
    const bf16* vSrcB = vSrcA + (size_t)32 * NSP;

    short8 qf[4][2];
#pragma unroll
    for (int qs = 0; qs < 4; qs++)
#pragma unroll
        for (int c = 0; c < 2; c++)
            qf[qs][c] = *(const short8*)(Qb + (size_t)(qb + qs * 16 + l15) * HDIM + c * 32 + quad * 8);

    f32x4 o[4][4];
    float lsum[4] = {0.f, 0.f, 0.f, 0.f};
#pragma unroll
    for (int qs = 0; qs < 4; qs++)
#pragma unroll
        for (int ds = 0; ds < 4; ds++) o[qs][ds] = (f32x4){0.f, 0.f, 0.f, 0.f};

    uint4 rKA, rKB, rVA, rVB;
#define ATTN_LOAD()                                         \
    rKA = *(const uint4*)kSrcA; kSrcA += 64 * HDIM;         \
    rKB = *(const uint4*)kSrcB; kSrcB += 64 * HDIM;         \
    rVA = *(const uint4*)vSrcA; vSrcA += 64;                \
    rVB = *(const uint4*)vSrcB; vSrcB += 64;
#define ATTN_STAGE(BUF)                                     \
    *(uint4*)&Ks[BUF][trow][tcol] = rKA;                    \
    *(uint4*)&Ks[BUF][32 + trow][tcol] = rKB;               \
    *(uint4*)&Vs[BUF][trow][tcol] = rVA;                    \
    *(uint4*)&Vs[BUF][32 + trow][tcol] = rVB;
#define ATTN_COMPUTE(BUF)                                                                \
    {                                                                                    \
        short8 kf[4][2], vf[4][2];                                                       \
        _Pragma("unroll")                                                                \
        for (int ms = 0; ms < 4; ms++)                                                   \
            _Pragma("unroll")                                                            \
            for (int c = 0; c < 2; c++)                                                  \
                kf[ms][c] = *(const short8*)&Ks[BUF][ms * 16 + l15][c * 32 + quad * 8];  \
        _Pragma("unroll")                                                                \
        for (int ds = 0; ds < 4; ds++)                                                   \
            _Pragma("unroll")                                                            \
            for (int c = 0; c < 2; c++)                                                  \
                vf[ds][c] = *(const short8*)&Vs[BUF][ds * 16 + l15][c * 32 + quad * 8];  \
        _Pragma("unroll")                                                                \
        for (int qs = 0; qs < 4; qs++) {                                                 \
            f32x4 s[4];                                                                  \
            __builtin_amdgcn_s_setprio(1);                                               \
            _Pragma("unroll")                                                            \
            for (int ms = 0; ms < 4; ms++) {                                             \
                f32x4 a = (f32x4){0.f, 0.f, 0.f, 0.f};                                   \
                a = __builtin_amdgcn_mfma_f32_16x16x32_bf16(kf[ms][0], qf[qs][0], a, 0, 0, 0); \
                a = __builtin_amdgcn_mfma_f32_16x16x32_bf16(kf[ms][1], qf[qs][1], a, 0, 0, 0); \
                s[ms] = a;                                                               \
            }                                                                            \
            __builtin_amdgcn_s_setprio(0);                                               \
            unsigned rr[4][2];                                                           \
            float ps = 0.f;                                                              \
            _Pragma("unroll")                                                            \
            for (int ms = 0; ms < 4; ms++) {                                             \
                float e0 = fexp2(s[ms][0]);                                              \
                float e1 = fexp2(s[ms][1]);                                              \
                float e2 = fexp2(s[ms][2]);                                              \
                float e3 = fexp2(s[ms][3]);                                              \
                ps += (e0 + e1) + (e2 + e3);                                             \
                asm("v_cvt_pk_bf16_f32 %0, %1, %2" : "=v"(rr[ms][0]) : "v"(e0), "v"(e1)); \
                asm("v_cvt_pk_bf16_f32 %0, %1, %2" : "=v"(rr[ms][1]) : "v"(e2), "v"(e3)); \
            }                                                                            \
            ps += __shfl_xor(ps, 16);                                                    \
            ps += __shfl_xor(ps, 32);                                                    \
            lsum[qs] += ps;                                                              \
            _Pragma("unroll")                                                            \
            for (int j = 0; j < 2; j++) {                                                \
                asm("v_permlane32_swap_b32 %0, %1" : "+v"(rr[0][j]), "+v"(rr[1][j]));    \
                asm("v_permlane32_swap_b32 %0, %1" : "+v"(rr[2][j]), "+v"(rr[3][j]));    \
            }                                                                            \
            _Pragma("unroll")                                                            \
            for (int j = 0; j < 2; j++) {                                                \
                asm("v_permlane16_swap_b32 %0, %1" : "+v"(rr[0][j]), "+v"(rr[1][j]));    \
                asm("v_permlane16_swap_b32 %0, %1" : "+v"(rr[2][j]), "+v"(rr[3][j]));    \
            }                                                                            \
            short8 pf0, pf1;                                                             \
            {                                                                            \
                unsigned* p0 = (unsigned*)&pf0;                                          \
                p0[0] = rr[0][0]; p0[1] = rr[0][1]; p0[2] = rr[1][0]; p0[3] = rr[1][1];  \
                unsigned* p1 = (unsigned*)&pf1;                                          \
                p1[0] = rr[2][0]; p1[1] = rr[2][1]; p1[2] = rr[3][0]; p1[3] = rr[3][1];  \
            }                                                                            \
            __builtin_amdgcn_s_setprio(1);                                               \
            _Pragma("unroll")                                                            \
            for (int ds = 0; ds < 4; ds++) {                                             \
                f32x4 a = o[qs][ds];                                                     \
                a = __builtin_amdgcn_mfma_f32_16x16x32_bf16(pf0, vf[ds][0], a, 0, 0, 0); \
                a = __builtin_amdgcn_mfma_f32_16x16x32_bf16(pf1, vf[ds][1], a, 0, 0, 0); \
                o[qs][ds] = a;                                                           \
            }                                                                            \
            __builtin_amdgcn_s_setprio(0);                                               \
        }                                                                                \
    }

    // prologue: tile0 -> buf0; issue tile1 loads
    ATTN_LOAD()                          // tile 0
    ATTN_STAGE(0)
    ATTN_LOAD()                          // tile 1
    __syncthreads();                     // buf0 visible

    for (int mt = 0; mt < MTN; mt += 2) {
        // phase A: stage tile mt+1 -> buf1 (regs), load tile mt+2, compute buf0
        ATTN_STAGE(1)
        ATTN_LOAD()
        ATTN_COMPUTE(0)
        __syncthreads();                 // buf1 visible
        // phase B: stage tile mt+2 -> buf0, load tile mt+3, compute buf1
        ATTN_STAGE(0)
        ATTN_LOAD()
        ATTN_COMPUTE(1)
        __syncthreads();                 // buf0 visible
    }
#undef ATTN_LOAD
#undef ATTN_STAGE
#undef ATTN_COMPUTE

    // epilogue: unnormalized partials (bf16 O, fp32 l)
#pragma unroll
    for (int qs = 0; qs < 4; qs++) {
#pragma unroll
        for (int ds = 0; ds < 4; ds++)
#pragma unroll
            for (int r = 0; r < 4; r++) {
                const int q = qb + qs * 16 + quad * 4 + r;
                unsigned u = pk1(o[qs][ds][r]);
                opart[((size_t)(spl * BATCH + b) * NSP + q) * CCH + h * 64 + ds * 16 + l15] =
                    *(bf16*)&u;
            }
        if (quad == 0) {
            const int q = qb + qs * 16 + l15;
            lpart[(((size_t)spl * BATCH + b) * NHEAD + h) * NSP + q] = lsum[qs];
        }
    }
}

// ---------------- combine the two key-splits -> att_t[b][n][c] bf16 ----------------
__global__ __launch_bounds__(256) void attn_combine(const bf16* __restrict__ opart,
                                                    const float* __restrict__ lpart,
                                                    bf16* __restrict__ att_t) {
    const int idx = blockIdx.x * 256 + threadIdx.x;   // 8 channels each
    const int c8 = (idx & 63) * 8;
    const int n  = (idx >> 6) & 4095;
    const int b  = idx >> 18;
    const int h  = c8 >> 6;
    float l = 0.f;
#pragma unroll
    for (int s = 0; s < NSPLIT; s++)
        l += lpart[(((size_t)s * BATCH + b) * NHEAD + h) * NSP + n];
    const float inv = 1.f / l;
    float acc[8] = {};
#pragma unroll
    for (int s = 0; s < NSPLIT; s++) {
        uint4 u = *(const uint4*)&opart[((size_t)(s * BATCH + b) * NSP + n) * CCH + c8];
        acc[0] += upk(u.x); acc[1] += upk(u.x >> 16);
        acc[2] += upk(u.y); acc[3] += upk(u.y >> 16);
        acc[4] += upk(u.z); acc[5] += upk(u.z >> 16);
        acc[6] += upk(u.w); acc[7] += upk(u.w >> 16);
    }
    uint4 o;
    o.x = pk2(acc[0] * inv, acc[1] * inv);
    o.y = pk2(acc[2] * inv, acc[3] * inv);
    o.z = pk2(acc[4] * inv, acc[5] * inv);
    o.w = pk2(acc[6] * inv, acc[7] * inv);
    *(uint4*)&att_t[((size_t)b * NSP + n) * CCH + c8] = o;
}

extern "C" void kernel_launch(void* const* d_in, const int* in_sizes, int n_in,
                              void* d_out, int out_size, void* d_ws, size_t ws_size,
                              hipStream_t stream) {
    const float* x    = (const float*)d_in[0];
    const float* nw   = (const float*)d_in[1];
    const float* nb   = (const float*)d_in[2];
    const float* qkvw = (const float*)d_in[3];
    const float* qkvb = (const float*)d_in[4];
    const float* pw   = (const float*)d_in[5];
    const float* pb   = (const float*)d_in[6];
    float* out = (float*)d_out;
    char* ws   = (char*)d_ws;

    float* sbuf = (float*)ws;                             // 8 KB partial stats
    bf16* wq  = (bf16*)(ws + (size_t)1  * 1024 * 1024);   // 1.5 MB
    bf16* wp  = (bf16*)(ws + (size_t)3  * 1024 * 1024);   // 0.5 MB
    bf16* hnt = (bf16*)(ws + (size_t)4  * 1024 * 1024);   // 8 MB, reused as att_t
    bf16* qtb = (bf16*)(ws + (size_t)12 * 1024 * 1024);   // 8 MB
    bf16* ktb = (bf16*)(ws + (size_t)20 * 1024 * 1024);   // 8 MB
    bf16* vtb = (bf16*)(ws + (size_t)28 * 1024 * 1024);   // 8 MB
    bf16* opart = (bf16*)(ws + (size_t)36 * 1024 * 1024); // 16.8 MB (2 splits, bf16)
    float* lpart = (float*)(ws + (size_t)56 * 1024 * 1024); // 0.5 MB
    bf16* att = hnt;

    hipLaunchKernelGGL(prep0, dim3(1024 + 1024), dim3(256), 0, stream,
                       x, qkvw, pw, sbuf, wq, wp);
    hipLaunchKernelGGL(gn_apply_t, dim3(NSP / 64, CCH / 64, BATCH), dim3(256), 0, stream,
                       x, sbuf, nw, nb, hnt);
    hipLaunchKernelGGL(gemm_qkv, dim3(NSP / 128, 1536 / 128, BATCH), dim3(256), 0, stream,
                       wq, hnt, qkvb, qtb, ktb, vtb);
    hipLaunchKernelGGL(attn10, dim3(512), dim3(256), 0, stream,
                       qtb, ktb, vtb, opart, lpart);
    hipLaunchKernelGGL(attn_combine, dim3(BATCH * NSP * CCH / 8 / 256), dim3(256), 0, stream,
                       opart, lpart, att);
    hipLaunchKernelGGL(gemm_proj, dim3(NSP / 128, CCH / 128, BATCH), dim3(256), 0, stream,
                       wp, att, pb, x, out);
}

// Round 15
// 200.941 us; speedup vs baseline: 1.6849x; 1.6849x over previous
//
#include <hip/hip_runtime.h>
#include <hip/hip_bf16.h>
#include <math.h>

#define BATCH 2
#define CCH   512
#define NSP   4096
#define NHEAD 8
#define HDIM  64
#define NGRP  32
#define CPG   16
#define EPSV  1e-5f
#define NSPLIT 2
#define MTN   (NSP / NSPLIT / 64)
#define SMSCALE 0.1803368801111204f   // 0.125 * log2(e): folded into Q at QKV epilogue

typedef __attribute__((ext_vector_type(8))) short short8;
typedef __attribute__((ext_vector_type(4))) short short4v;
typedef __attribute__((ext_vector_type(4))) float f32x4;
typedef __hip_bfloat16 bf16;

// pack two fp32 -> two bf16 in a u32 (approx-RNE via +0x8000; no NaN/Inf in our paths)
static __device__ __forceinline__ unsigned pk2(float a, float b) {
    return ((__float_as_uint(a) + 0x8000u) >> 16) |
           ((__float_as_uint(b) + 0x8000u) & 0xFFFF0000u);
}
static __device__ __forceinline__ unsigned pk1(float a) {
    return (__float_as_uint(a) + 0x8000u) >> 16;
}
static __device__ __forceinline__ float upk(unsigned u) {   // low 16 bits -> float
    unsigned v = u << 16;
    return __uint_as_float(v);
}
static __device__ __forceinline__ float fexp2(float x) {
    return __builtin_amdgcn_exp2f(x);   // v_exp_f32, 1 instr
}
// async global->LDS, 16B per lane. LDS base must be WAVE-UNIFORM; HW writes
// lane i's 16B at base + i*16. Global src is per-lane.
static __device__ __forceinline__ void gload16(const bf16* g, bf16* l) {
    __builtin_amdgcn_global_load_lds(
        (const __attribute__((address_space(1))) unsigned*)g,
        (__attribute__((address_space(3))) unsigned*)l, 16, 0, 0);
}

// ---------------- fused: GroupNorm partial stats (blocks 0..1023) + weight cast ----------------
__global__ __launch_bounds__(256) void prep0(const float* __restrict__ x,
                                             const float* __restrict__ qkvw,
                                             const float* __restrict__ pw,
                                             float* __restrict__ sbuf,
                                             bf16* __restrict__ wq, bf16* __restrict__ wp) {
    if (blockIdx.x < 1024) {
        const int bg = blockIdx.x >> 4, sub = blockIdx.x & 15;
        const float4* p = (const float4*)(x + (size_t)bg * (CPG * NSP)) +
                          (size_t)sub * (CPG * NSP / 4 / 16);
        float s = 0.f, ss = 0.f;
#pragma unroll
        for (int it = 0; it < 4; it++) {                 // 1024 float4 / 256 threads
            float4 v = p[it * 256 + threadIdx.x];
            s  += v.x + v.y + v.z + v.w;
            ss += v.x * v.x + v.y * v.y + v.z * v.z + v.w * v.w;
        }
        for (int o = 32; o > 0; o >>= 1) {
            s  += __shfl_down(s, o);
            ss += __shfl_down(ss, o);
        }
        __shared__ float shs[4], shss[4];
        const int wid = threadIdx.x >> 6, lane = threadIdx.x & 63;
        if (lane == 0) { shs[wid] = s; shss[wid] = ss; }
        __syncthreads();
        if (threadIdx.x == 0) {
            s  = shs[0] + shs[1] + shs[2] + shs[3];
            ss = shss[0] + shss[1] + shss[2] + shss[3];
            sbuf[bg * 16 + sub]        = s;
            sbuf[1024 + bg * 16 + sub] = ss;
        }
    } else {
        const int i = (blockIdx.x - 1024) * 256 + threadIdx.x;   // float4 index
        const int NQ = 1536 * 512 / 4;
        float4 v; bf16* dst; int di;
        if (i < NQ) { v = ((const float4*)qkvw)[i]; dst = wq; di = i; }
        else        { v = ((const float4*)pw)[i - NQ]; dst = wp; di = i - NQ; }
        uint2 o = {pk2(v.x, v.y), pk2(v.z, v.w)};
        *(uint2*)(dst + (size_t)di * 4) = o;
    }
}

// ---------------- GroupNorm finalize + apply + transpose + cast: hnt[b][n][c] bf16 ----------------
__global__ __launch_bounds__(256) void gn_apply_t(const float* __restrict__ x,
                                                  const float* __restrict__ sbuf,
                                                  const float* __restrict__ nw,
                                                  const float* __restrict__ nb,
                                                  bf16* __restrict__ hnt) {
    __shared__ float Ls[64][68];
    __shared__ float Gmu[4], Grs[4];
    const int b  = blockIdx.z;
    const int c0 = blockIdx.y * 64;
    const int n0 = blockIdx.x * 64;
    const int t  = threadIdx.x;
    const int cl = t >> 4, n4 = (t & 15) * 4;
    if (t < 4) {
        const int bg = b * NGRP + (c0 >> 4) + t;
        float s = 0.f, ss = 0.f;
#pragma unroll
        for (int i = 0; i < 16; i++) {
            s  += sbuf[bg * 16 + i];
            ss += sbuf[1024 + bg * 16 + i];
        }
        const float invn = 1.f / (float)(CPG * NSP);
        const float mu = s * invn;
        Gmu[t] = mu;
        Grs[t] = rsqrtf(ss * invn - mu * mu + EPSV);
    }
    __syncthreads();
#pragma unroll
    for (int ph = 0; ph < 4; ph++) {
        const int c  = c0 + ph * 16 + cl;
        const float mu = Gmu[ph], rs = Grs[ph];
        const float sw = nw[c] * rs;
        const float sb = nb[c] - mu * sw;
        float4 v = *(const float4*)&x[((size_t)b * CCH + c) * NSP + n0 + n4];
        float4 o;
        o.x = v.x * sw + sb; o.y = v.y * sw + sb;
        o.z = v.z * sw + sb; o.w = v.w * sw + sb;
        *(float4*)&Ls[ph * 16 + cl][n4] = o;
    }
    __syncthreads();
#pragma unroll
    for (int ph = 0; ph < 2; ph++) {
        const int task = ph * 256 + t;
        const int nl = task & 63, cc = (task >> 6) * 8;
        uint4 o;
        o.x = pk2(Ls[cc + 0][nl], Ls[cc + 1][nl]);
        o.y = pk2(Ls[cc + 2][nl], Ls[cc + 3][nl]);
        o.z = pk2(Ls[cc + 4][nl], Ls[cc + 5][nl]);
        o.w = pk2(Ls[cc + 6][nl], Ls[cc + 7][nl]);
        *(uint4*)&hnt[((size_t)b * NSP + n0 + nl) * CCH + c0 + cc] = o;
    }
}

// ---------------- bf16 MFMA GEMM v2 (128x128): LDS double-buffer + global_load_lds ----------------
#define GEMM_STAGE(CUR)                                         \
    gload16(aSrc0, &As[CUR][(wave * 16) * 32]);                 \
    gload16(aSrc1, &As[CUR][(64 + wave * 16) * 32]);            \
    gload16(bSrc0, &Bs[CUR][(wave * 16) * 32]);                 \
    gload16(bSrc1, &Bs[CUR][(64 + wave * 16) * 32]);            \
    aSrc0 += 32; aSrc1 += 32; bSrc0 += 32; bSrc1 += 32;

#define GEMM_MAIN(Wptr, Xptr)                                                            \
    __shared__ __align__(16) bf16 As[2][128 * 32];                                       \
    __shared__ __align__(16) bf16 Bs[2][128 * 32];                                       \
    const int t = threadIdx.x, wave = t >> 6, lane = t & 63;                             \
    const int quad = lane >> 4, l15 = lane & 15;                                         \
    const int srow = lane >> 2, scol = (lane & 3) * 8;                                   \
    const int b   = blockIdx.z;                                                          \
    const int wm = wave >> 1, wn = wave & 1;                                             \
    const int m0w = blockIdx.y * 128 + wm * 64;                                          \
    const int n0w = blockIdx.x * 128 + wn * 64;                                          \
    const bf16* aSrc0 = Wptr + (size_t)(blockIdx.y * 128 + wave * 16 + srow) * 512 + scol; \
    const bf16* aSrc1 = aSrc0 + (size_t)64 * 512;                                        \
    const bf16* bSrc0 = Xptr + ((size_t)b * NSP + blockIdx.x * 128 + wave * 16 + srow) * 512 + scol; \
    const bf16* bSrc1 = bSrc0 + (size_t)64 * 512;                                        \
    f32x4 acc[4][4];                                                                     \
    _Pragma("unroll")                                                                    \
    for (int i = 0; i < 4; i++)                                                          \
        _Pragma("unroll")                                                                \
        for (int j = 0; j < 4; j++) acc[i][j] = (f32x4){0.f, 0.f, 0.f, 0.f};             \
    GEMM_STAGE(0)                                                                        \
    __syncthreads();                                                                     \
    _Pragma("unroll")                                                                    \
    for (int ks = 0; ks < 16; ks++) {                                                    \
        const int cur = ks & 1;                                                          \
        if (ks < 15) { GEMM_STAGE(cur ^ 1) }                                             \
        short8 af[4], bfr[4];                                                            \
        _Pragma("unroll")                                                                \
        for (int mf = 0; mf < 4; mf++)                                                   \
            af[mf] = *(const short8*)&As[cur][(wm * 64 + mf * 16 + l15) * 32 + quad * 8]; \
        _Pragma("unroll")                                                                \
        for (int nf = 0; nf < 4; nf++)                                                   \
            bfr[nf] = *(const short8*)&Bs[cur][(wn * 64 + nf * 16 + l15) * 32 + quad * 8]; \
        _Pragma("unroll")                                                                \
        for (int mf = 0; mf < 4; mf++)                                                   \
            _Pragma("unroll")                                                            \
            for (int nf = 0; nf < 4; nf++)                                               \
                acc[mf][nf] = __builtin_amdgcn_mfma_f32_16x16x32_bf16(af[mf], bfr[nf],   \
                                                                      acc[mf][nf], 0, 0, 0); \
        __syncthreads();                                                                 \
    }

__global__ __launch_bounds__(256) void gemm_qkv(const bf16* __restrict__ Wb,
                                                const bf16* __restrict__ Xt,
                                                const float* __restrict__ bias,
                                                bf16* __restrict__ qt, bf16* __restrict__ kt,
                                                bf16* __restrict__ vt) {
    GEMM_MAIN(Wb, Xt)

    const int sec = m0w >> 9, h = (m0w >> 6) & 7, bh = b * NHEAD + h;
    const float sm = (sec == 0) ? SMSCALE : 1.0f;
    float bi[4][4];
#pragma unroll
    for (int mf = 0; mf < 4; mf++)
#pragma unroll
        for (int r = 0; r < 4; r++) bi[mf][r] = bias[m0w + mf * 16 + quad * 4 + r];

    if (sec < 2) {
        bf16* dst = (sec == 0) ? qt : kt;   // [bh][n][d], d = mf*16+quad*4+r: 4 consecutive
#pragma unroll
        for (int mf = 0; mf < 4; mf++)
#pragma unroll
            for (int nf = 0; nf < 4; nf++) {
                const int n = n0w + nf * 16 + l15;
                float v0 = (acc[mf][nf][0] + bi[mf][0]) * sm;
                float v1 = (acc[mf][nf][1] + bi[mf][1]) * sm;
                float v2 = (acc[mf][nf][2] + bi[mf][2]) * sm;
                float v3 = (acc[mf][nf][3] + bi[mf][3]) * sm;
                uint2 o = {pk2(v0, v1), pk2(v2, v3)};
                *(uint2*)(dst + ((size_t)bh * NSP + n) * HDIM + mf * 16 + quad * 4) = o;
            }
    } else {
#pragma unroll
        for (int mf = 0; mf < 4; mf++)
#pragma unroll
            for (int nf = 0; nf < 4; nf++)
#pragma unroll
                for (int r = 0; r < 4; r++) {
                    const float v = acc[mf][nf][r] + bi[mf][r];
                    const int n = n0w + nf * 16 + l15;
                    const int d = mf * 16 + quad * 4 + r;
                    unsigned u = pk1(v);
                    vt[((size_t)bh * HDIM + d) * NSP + n] = *(bf16*)&u;
                }
    }
}

// r13: LDS-transposed epilogue for proj — perfect float4 streams on out/resid.
__global__ __launch_bounds__(256) void gemm_proj(const bf16* __restrict__ Wb,
                                                 const bf16* __restrict__ Xt,
                                                 const float* __restrict__ bias,
                                                 const float* __restrict__ resid,
                                                 float* __restrict__ out) {
    GEMM_MAIN(Wb, Xt)

    float bi[4][4];
#pragma unroll
    for (int mf = 0; mf < 4; mf++)
#pragma unroll
        for (int r = 0; r < 4; r++) bi[mf][r] = bias[m0w + mf * 16 + quad * 4 + r];

    float* scratch = (float*)As;         // 4096 fp32; safe after final barrier
    const int n0 = blockIdx.x * 128;
#pragma unroll
    for (int p = 0; p < 4; p++) {
        if (wm == (p >> 1)) {
#pragma unroll
            for (int ml = 0; ml < 2; ml++) {
                const int mf = (p & 1) * 2 + ml;
#pragma unroll
                for (int nf = 0; nf < 4; nf++)
#pragma unroll
                    for (int r = 0; r < 4; r++)
                        scratch[(ml * 16 + quad * 4 + r) * 128 + wn * 64 + nf * 16 + l15] =
                            acc[mf][nf][r] + bi[mf][r];
            }
        }
        __syncthreads();
#pragma unroll
        for (int i = 0; i < 4; i++) {
            const int idx = i * 256 + t;     // 0..1023
            const int row = idx >> 5, c4 = idx & 31;
            const int m = blockIdx.y * 128 + p * 32 + row;
            const size_t off = ((size_t)b * CCH + m) * NSP + n0 + c4 * 4;
            float4 rv = *(const float4*)&resid[off];
            float4 sv = *(const float4*)&scratch[row * 128 + c4 * 4];
            float4 ov;
            ov.x = sv.x + rv.x; ov.y = sv.y + rv.y;
            ov.z = sv.z + rv.z; ov.w = sv.w + rv.w;
            *(float4*)&out[off] = ov;
        }
        __syncthreads();
    }
}

// ---------------- MFMA flash attention v14 (r12/r13-exact): K/V dbuf, 1 barrier/tile ----------------
// r14 post-mortem: replacing the ol-MFMA rowsum with a per-tile VALU+shfl rowsum
// spilled the accumulators to scratch (FETCH 341MB / WRITE 432MB, attn 81->215µs).
// The ones-MFMA rowsum is the allocator-friendly form. Reverted to r13-exact.
__global__ __launch_bounds__(256, 2) void attn10(const bf16* __restrict__ qt,
                                                 const bf16* __restrict__ kt,
                                                 const bf16* __restrict__ vt,
                                                 bf16* __restrict__ opart,
                                                 float* __restrict__ lpart) {
    __shared__ __align__(16) bf16 Ks[2][64][68];
    __shared__ __align__(16) bf16 Vs[2][64][68];
    const int t = threadIdx.x, wave = t >> 6, lane = t & 63;
    const int quad = lane >> 4, l15 = lane & 15;
    const int blk = blockIdx.x;            // 0..511
    const int xcd = blk & 7, slot = blk >> 3;       // slot 0..63
    const int qtile = slot & 15;                    // 16 q-tiles of 256
    const int grp = xcd + 8 * (slot >> 4);          // 0..31 = (bh, spl)
    const int spl = grp & 1, bh = grp >> 1;
    const int b = bh >> 3, h = bh & 7;
    const int qb  = qtile * 256 + wave * 64;
    const int kb0 = spl * (NSP / NSPLIT);

    const bf16* Qb = qt + (size_t)bh * NSP * HDIM;

    // staging assignment: thread t -> 4 x 16B chunks (2 K row-halves, 2 V)
    const int trow = t >> 3;          // 0..31
    const int tcol = (t & 7) * 8;     // element offset in 64-elem row
    const bf16* kSrcA = kt + (size_t)bh * NSP * HDIM + (size_t)(kb0 + trow) * HDIM + tcol;
    const bf16* kSrcB = kSrcA + 32 * HDIM;
    const bf16* vSrcA = vt + (size_t)bh * HDIM * NSP + (size_t)trow * NSP + kb0 + tcol;
    const bf16* vSrcB = vSrcA + (size_t)32 * NSP;

    short8 qf[4][2];
#pragma unroll
    for (int qs = 0; qs < 4; qs++)
#pragma unroll
        for (int c = 0; c < 2; c++)
            qf[qs][c] = *(const short8*)(Qb + (size_t)(qb + qs * 16 + l15) * HDIM + c * 32 + quad * 8);

    short8 onesf;
    {
        const short one = (short)0x3F80;
        short8 o1 = {one, one, one, one, one, one, one, one};
        short8 zz = {0, 0, 0, 0, 0, 0, 0, 0};
        onesf = (l15 == 0) ? o1 : zz;
    }

    f32x4 o[4][4], ol[4];
#pragma unroll
    for (int qs = 0; qs < 4; qs++) {
        ol[qs] = (f32x4){0.f, 0.f, 0.f, 0.f};
#pragma unroll
        for (int ds = 0; ds < 4; ds++) o[qs][ds] = (f32x4){0.f, 0.f, 0.f, 0.f};
    }

    uint4 rKA, rKB, rVA, rVB;
#define ATTN_LOAD()                                         \
    rKA = *(const uint4*)kSrcA; kSrcA += 64 * HDIM;         \
    rKB = *(const uint4*)kSrcB; kSrcB += 64 * HDIM;         \
    rVA = *(const uint4*)vSrcA; vSrcA += 64;                \
    rVB = *(const uint4*)vSrcB; vSrcB += 64;
#define ATTN_STAGE(BUF)                                     \
    *(uint4*)&Ks[BUF][trow][tcol] = rKA;                    \
    *(uint4*)&Ks[BUF][32 + trow][tcol] = rKB;               \
    *(uint4*)&Vs[BUF][trow][tcol] = rVA;                    \
    *(uint4*)&Vs[BUF][32 + trow][tcol] = rVB;
#define ATTN_COMPUTE(BUF)                                                                \
    {                                                                                    \
        short8 kf[4][2], vf[4][2];                                                       \
        _Pragma("unroll")                                                                \
        for (int ms = 0; ms < 4; ms++)                                                   \
            _Pragma("unroll")                                                            \
            for (int c = 0; c < 2; c++)                                                  \
                kf[ms][c] = *(const short8*)&Ks[BUF][ms * 16 + l15][c * 32 + quad * 8];  \
        _Pragma("unroll")                                                                \
        for (int ds = 0; ds < 4; ds++)                                                   \
            _Pragma("unroll")                                                            \
            for (int c = 0; c < 2; c++)                                                  \
                vf[ds][c] = *(const short8*)&Vs[BUF][ds * 16 + l15][c * 32 + quad * 8];  \
        _Pragma("unroll")                                                                \
        for (int qs = 0; qs < 4; qs++) {                                                 \
            f32x4 s[4];                                                                  \
            __builtin_amdgcn_s_setprio(1);                                               \
            _Pragma("unroll")                                                            \
            for (int ms = 0; ms < 4; ms++) {                                             \
                f32x4 a = (f32x4){0.f, 0.f, 0.f, 0.f};                                   \
                a = __builtin_amdgcn_mfma_f32_16x16x32_bf16(kf[ms][0], qf[qs][0], a, 0, 0, 0); \
                a = __builtin_amdgcn_mfma_f32_16x16x32_bf16(kf[ms][1], qf[qs][1], a, 0, 0, 0); \
                s[ms] = a;                                                               \
            }                                                                            \
            __builtin_amdgcn_s_setprio(0);                                               \
            unsigned rr[4][2];                                                           \
            _Pragma("unroll")                                                            \
            for (int ms = 0; ms < 4; ms++) {                                             \
                float e0 = fexp2(s[ms][0]);                                              \
                float e1 = fexp2(s[ms][1]);                                              \
                float e2 = fexp2(s[ms][2]);                                              \
                float e3 = fexp2(s[ms][3]);                                              \
                asm("v_cvt_pk_bf16_f32 %0, %1, %2" : "=v"(rr[ms][0]) : "v"(e0), "v"(e1)); \
                asm("v_cvt_pk_bf16_f32 %0, %1, %2" : "=v"(rr[ms][1]) : "v"(e2), "v"(e3)); \
            }                                                                            \
            _Pragma("unroll")                                                            \
            for (int j = 0; j < 2; j++) {                                                \
                asm("v_permlane32_swap_b32 %0, %1" : "+v"(rr[0][j]), "+v"(rr[1][j]));    \
                asm("v_permlane32_swap_b32 %0, %1" : "+v"(rr[2][j]), "+v"(rr[3][j]));    \
            }                                                                            \
            _Pragma("unroll")                                                            \
            for (int j = 0; j < 2; j++) {                                                \
                asm("v_permlane16_swap_b32 %0, %1" : "+v"(rr[0][j]), "+v"(rr[1][j]));    \
                asm("v_permlane16_swap_b32 %0, %1" : "+v"(rr[2][j]), "+v"(rr[3][j]));    \
            }                                                                            \
            short8 pf0, pf1;                                                             \
            {                                                                            \
                unsigned* p0 = (unsigned*)&pf0;                                          \
                p0[0] = rr[0][0]; p0[1] = rr[0][1]; p0[2] = rr[1][0]; p0[3] = rr[1][1];  \
                unsigned* p1 = (unsigned*)&pf1;                                          \
                p1[0] = rr[2][0]; p1[1] = rr[2][1]; p1[2] = rr[3][0]; p1[3] = rr[3][1];  \
            }                                                                            \
            __builtin_amdgcn_s_setprio(1);                                               \
            _Pragma("unroll")                                                            \
            for (int ds = 0; ds < 4; ds++) {                                             \
                f32x4 a = o[qs][ds];                                                     \
                a = __builtin_amdgcn_mfma_f32_16x16x32_bf16(pf0, vf[ds][0], a, 0, 0, 0); \
                a = __builtin_amdgcn_mfma_f32_16x16x32_bf16(pf1, vf[ds][1], a, 0, 0, 0); \
                o[qs][ds] = a;                                                           \
            }                                                                            \
            {                                                                            \
                f32x4 a = ol[qs];                                                        \
                a = __builtin_amdgcn_mfma_f32_16x16x32_bf16(pf0, onesf, a, 0, 0, 0);     \
                a = __builtin_amdgcn_mfma_f32_16x16x32_bf16(pf1, onesf, a, 0, 0, 0);     \
                ol[qs] = a;                                                              \
            }                                                                            \
            __builtin_amdgcn_s_setprio(0);                                               \
        }                                                                                \
    }

    // prologue: tile0 -> buf0; issue tile1 loads
    ATTN_LOAD()                          // tile 0
    ATTN_STAGE(0)
    ATTN_LOAD()                          // tile 1
    __syncthreads();                     // buf0 visible

    for (int mt = 0; mt < MTN; mt += 2) {
        // phase A: stage tile mt+1 -> buf1 (regs), load tile mt+2, compute buf0
        ATTN_STAGE(1)
        ATTN_LOAD()
        ATTN_COMPUTE(0)
        __syncthreads();                 // buf1 visible
        // phase B: stage tile mt+2 -> buf0, load tile mt+3, compute buf1
        ATTN_STAGE(0)
        ATTN_LOAD()
        ATTN_COMPUTE(1)
        __syncthreads();                 // buf0 visible
    }
#undef ATTN_LOAD
#undef ATTN_STAGE
#undef ATTN_COMPUTE

    // epilogue: unnormalized partials (bf16 O, fp32 l)
#pragma unroll
    for (int qs = 0; qs < 4; qs++) {
#pragma unroll
        for (int ds = 0; ds < 4; ds++)
#pragma unroll
            for (int r = 0; r < 4; r++) {
                const int q = qb + qs * 16 + quad * 4 + r;
                unsigned u = pk1(o[qs][ds][r]);
                opart[((size_t)(spl * BATCH + b) * NSP + q) * CCH + h * 64 + ds * 16 + l15] =
                    *(bf16*)&u;
            }
        if (l15 == 0) {
#pragma unroll
            for (int r = 0; r < 4; r++) {
                const int q = qb + qs * 16 + quad * 4 + r;
                lpart[(((size_t)spl * BATCH + b) * NHEAD + h) * NSP + q] = ol[qs][r];
            }
        }
    }
}

// ---------------- combine the two key-splits -> att_t[b][n][c] bf16 ----------------
__global__ __launch_bounds__(256) void attn_combine(const bf16* __restrict__ opart,
                                                    const float* __restrict__ lpart,
                                                    bf16* __restrict__ att_t) {
    const int idx = blockIdx.x * 256 + threadIdx.x;   // 8 channels each
    const int c8 = (idx & 63) * 8;
    const int n  = (idx >> 6) & 4095;
    const int b  = idx >> 18;
    const int h  = c8 >> 6;
    float l = 0.f;
#pragma unroll
    for (int s = 0; s < NSPLIT; s++)
        l += lpart[(((size_t)s * BATCH + b) * NHEAD + h) * NSP + n];
    const float inv = 1.f / l;
    float acc[8] = {};
#pragma unroll
    for (int s = 0; s < NSPLIT; s++) {
        uint4 u = *(const uint4*)&opart[((size_t)(s * BATCH + b) * NSP + n) * CCH + c8];
        acc[0] += upk(u.x); acc[1] += upk(u.x >> 16);
        acc[2] += upk(u.y); acc[3] += upk(u.y >> 16);
        acc[4] += upk(u.z); acc[5] += upk(u.z >> 16);
        acc[6] += upk(u.w); acc[7] += upk(u.w >> 16);
    }
    uint4 o;
    o.x = pk2(acc[0] * inv, acc[1] * inv);
    o.y = pk2(acc[2] * inv, acc[3] * inv);
    o.z = pk2(acc[4] * inv, acc[5] * inv);
    o.w = pk2(acc[6] * inv, acc[7] * inv);
    *(uint4*)&att_t[((size_t)b * NSP + n) * CCH + c8] = o;
}

extern "C" void kernel_launch(void* const* d_in, const int* in_sizes, int n_in,
                              void* d_out, int out_size, void* d_ws, size_t ws_size,
                              hipStream_t stream) {
    const float* x    = (const float*)d_in[0];
    const float* nw   = (const float*)d_in[1];
    const float* nb   = (const float*)d_in[2];
    const float* qkvw = (const float*)d_in[3];
    const float* qkvb = (const float*)d_in[4];
    const float* pw   = (const float*)d_in[5];
    const float* pb   = (const float*)d_in[6];
    float* out = (float*)d_out;
    char* ws   = (char*)d_ws;

    float* sbuf = (float*)ws;                             // 8 KB partial stats
    bf16* wq  = (bf16*)(ws + (size_t)1  * 1024 * 1024);   // 1.5 MB
    bf16* wp  = (bf16*)(ws + (size_t)3  * 1024 * 1024);   // 0.5 MB
    bf16* hnt = (bf16*)(ws + (size_t)4  * 1024 * 1024);   // 8 MB, reused as att_t
    bf16* qtb = (bf16*)(ws + (size_t)12 * 1024 * 1024);   // 8 MB
    bf16* ktb = (bf16*)(ws + (size_t)20 * 1024 * 1024);   // 8 MB
    bf16* vtb = (bf16*)(ws + (size_t)28 * 1024 * 1024);   // 8 MB
    bf16* opart = (bf16*)(ws + (size_t)36 * 1024 * 1024); // 16.8 MB (2 splits, bf16)
    float* lpart = (float*)(ws + (size_t)56 * 1024 * 1024); // 0.5 MB
    bf16* att = hnt;

    hipLaunchKernelGGL(prep0, dim3(1024 + 1024), dim3(256), 0, stream,
                       x, qkvw, pw, sbuf, wq, wp);
    hipLaunchKernelGGL(gn_apply_t, dim3(NSP / 64, CCH / 64, BATCH), dim3(256), 0, stream,
                       x, sbuf, nw, nb, hnt);
    hipLaunchKernelGGL(gemm_qkv, dim3(NSP / 128, 1536 / 128, BATCH), dim3(256), 0, stream,
                       wq, hnt, qkvb, qtb, ktb, vtb);
    hipLaunchKernelGGL(attn10, dim3(512), dim3(256), 0, stream,
                       qtb, ktb, vtb, opart, lpart);
    hipLaunchKernelGGL(attn_combine, dim3(BATCH * NSP * CCH / 8 / 256), dim3(256), 0, stream,
                       opart, lpart, att);
    hipLaunchKernelGGL(gemm_proj, dim3(NSP / 128, CCH / 128, BATCH), dim3(256), 0, stream,
                       wp, att, pb, x, out);
}